// Round 7
// baseline (244.731 us; speedup 1.0000x reference)
//
#include <hip/hip_runtime.h>

#define H2    1024
#define LSRC  1024
#define BATCH 64
#define NCH   32            // l-chunks
#define CH    32            // LSRC / NCH, rows per block

__device__ __forceinline__ float fast_tanh(float x) {
  // tanh(x) = 1 - 2/(exp(2x)+1); saturates correctly (exp->inf => 1, exp->0 => -1)
  float e2 = __expf(2.0f * x);
  return 1.0f - 2.0f * __builtin_amdgcn_rcpf(e2 + 1.0f);
}

// -------- BW probe: m13-replica grid-stride pure read of ef + eo (512 MB).
// Known-good coalesced pattern; writes 1 float/thread (into part area, which
// fused_kernel fully overwrites afterwards). Measures the harness's actual
// achievable read bandwidth on these exact buffers.
__global__ __launch_bounds__(256) void probe_kernel(
    const float4* __restrict__ a, const float4* __restrict__ b,
    float* __restrict__ outp) {
  const size_t tid = (size_t)blockIdx.x * 256 + threadIdx.x;
  const size_t nthr = (size_t)gridDim.x * 256;
  const size_t N = (size_t)BATCH * LSRC * 256;  // 16.78M float4 per buffer
  float4 s = {0.f, 0.f, 0.f, 0.f};
  for (size_t i = tid; i < N; i += nthr) {
    float4 x = a[i];
    float4 y = b[i];
    s.x += x.x + y.x; s.y += x.y + y.y;
    s.z += x.z + y.z; s.w += x.w + y.w;
  }
  outp[tid] = s.x + s.y + s.z + s.w;
}

// dec[b][h] = sum_k s[b][k] * W[h][k] + bias[h]
__global__ __launch_bounds__(256) void dec_kernel(
    const float* __restrict__ s, const float* __restrict__ W,
    const float* __restrict__ bias, float* __restrict__ dec) {
  const int KT = 128;
  __shared__ float s_lds[BATCH][KT + 1];
  __shared__ float w_lds[16][KT];
  const int t  = threadIdx.x;
  const int h0 = blockIdx.x * 16;
  const int bi = t & 63;
  const int hg = t >> 6;  // 0..3
  float acc[4] = {0.f, 0.f, 0.f, 0.f};
  for (int k0 = 0; k0 < H2; k0 += KT) {
    __syncthreads();
    for (int idx = t; idx < BATCH * KT; idx += 256) {
      int r = idx >> 7, c = idx & (KT - 1);
      s_lds[r][c] = s[r * H2 + k0 + c];
    }
    for (int idx = t; idx < 16 * KT; idx += 256) {
      int r = idx >> 7, c = idx & (KT - 1);
      w_lds[r][c] = W[(h0 + r) * H2 + k0 + c];
    }
    __syncthreads();
    for (int k = 0; k < KT; ++k) {
      float sv = s_lds[bi][k];
#pragma unroll
      for (int j = 0; j < 4; ++j) acc[j] += sv * w_lds[hg + 4 * j][k];
    }
  }
#pragma unroll
  for (int j = 0; j < 4; ++j) {
    int h = h0 + hg + 4 * j;
    dec[bi * H2 + h] = acc[j] + bias[h];
  }
}

// Fused e + shift-free softmax weight + weighted-eo partial, per (l-chunk, b).
// (round-4 exact version: passed, fused ~153.7 us)
__global__ __launch_bounds__(256) void fused_kernel(
    const float* __restrict__ ef, const float* __restrict__ eo,
    const float* __restrict__ dec, const float* __restrict__ v,
    const float* __restrict__ mask, float* __restrict__ part,
    float* __restrict__ sums) {
  __shared__ float dv_lds[2 * H2];  // dec[b][0..1023] | v[0..1023]
  __shared__ float a_lds[CH];
  __shared__ float wpsum[4];
  const int t    = threadIdx.x;
  const int lane = t & 63;
  const int wave = t >> 6;
  const int lc   = blockIdx.x;
  const int b    = blockIdx.y;
  const int l0   = lc * CH;

  ((float4*)dv_lds)[t]       = ((const float4*)(dec + (size_t)b * H2))[t];
  ((float4*)dv_lds)[256 + t] = ((const float4*)v)[t];
  __syncthreads();

  // ---- phase A: w[l] = exp(e[l])*mask[l] for CH rows; chunk-sum -> sums ----
  const float4* efb = (const float4*)(ef) + ((size_t)b * LSRC + l0) * 256;
  float lsum = 0.f;
#pragma unroll
  for (int i = 0; i < CH / 4; ++i) {
    const int rl = wave + 4 * i;
    const float4* row = efb + (size_t)rl * 256;
    float sum = 0.f;
#pragma unroll
    for (int j = 0; j < 4; ++j) {
      float4 x  = row[lane + 64 * j];
      float4 dj = ((const float4*)dv_lds)[lane + 64 * j];
      float4 vj = ((const float4*)dv_lds)[256 + lane + 64 * j];
      sum += fast_tanh(x.x + dj.x) * vj.x;
      sum += fast_tanh(x.y + dj.y) * vj.y;
      sum += fast_tanh(x.z + dj.z) * vj.z;
      sum += fast_tanh(x.w + dj.w) * vj.w;
    }
#pragma unroll
    for (int off = 32; off; off >>= 1) sum += __shfl_xor(sum, off);
    float mk = mask[b * LSRC + l0 + rl];
    if (lane == 0) {
      float w = __expf(fminf(sum, 80.f)) * mk;
      a_lds[rl] = w;
      lsum += w;
    }
  }
  if (lane == 0) wpsum[wave] = lsum;
  __syncthreads();
  if (t == 0) sums[b * NCH + lc] = wpsum[0] + wpsum[1] + wpsum[2] + wpsum[3];

  // ---- phase B: part[lc][b][h] = sum_l w[l] * eo[b][l][h] ----
  const float4* eob = (const float4*)(eo) + ((size_t)b * LSRC + l0) * 256;
  float4 acc = {0.f, 0.f, 0.f, 0.f};
#pragma unroll 8
  for (int l = 0; l < CH; ++l) {
    float  a = a_lds[l];
    float4 x = eob[(size_t)l * 256 + t];
    acc.x += a * x.x; acc.y += a * x.y; acc.z += a * x.z; acc.w += a * x.w;
  }
  ((float4*)(part) + (size_t)(lc * BATCH + b) * 256)[t] = acc;
}

// out[b][h] = (sum_lc part[lc][b][h]) / (sum_lc sums[b][lc])
__global__ __launch_bounds__(256) void reduce_kernel(
    const float* __restrict__ part, const float* __restrict__ sums,
    float* __restrict__ out) {
  const int b = blockIdx.x, t = threadIdx.x;
  float Z = 0.f;
#pragma unroll
  for (int lc = 0; lc < NCH; ++lc) Z += sums[b * NCH + lc];
  float inv = 1.0f / Z;
  float4 s = {0.f, 0.f, 0.f, 0.f};
#pragma unroll
  for (int lc = 0; lc < NCH; ++lc) {
    float4 x = ((const float4*)(part) + (size_t)(lc * BATCH + b) * 256)[t];
    s.x += x.x; s.y += x.y; s.z += x.z; s.w += x.w;
  }
  float4 o = {s.x * inv, s.y * inv, s.z * inv, s.w * inv};
  ((float4*)(out) + (size_t)b * 256)[t] = o;
}

extern "C" void kernel_launch(void* const* d_in, const int* in_sizes, int n_in,
                              void* d_out, int out_size, void* d_ws, size_t ws_size,
                              hipStream_t stream) {
  const float* s_t_hat  = (const float*)d_in[0];
  const float* enc_out  = (const float*)d_in[1];
  const float* enc_feat = (const float*)d_in[2];
  const float* mask     = (const float*)d_in[3];
  const float* W        = (const float*)d_in[4];
  const float* bias     = (const float*)d_in[5];
  const float* v        = (const float*)d_in[6];
  float* out = (float*)d_out;

  // ws layout (fp32): dec[64K] | sums[2K] | part[32*64K]  (~8.5 MB)
  float* dec  = (float*)d_ws;
  float* sums = dec + BATCH * H2;
  float* part = sums + BATCH * NCH;

  // BW probe first; its 2MB output goes into part, fully overwritten below.
  probe_kernel<<<2048, 256, 0, stream>>>(
      (const float4*)enc_feat, (const float4*)enc_out, part);
  dec_kernel<<<H2 / 16, 256, 0, stream>>>(s_t_hat, W, bias, dec);
  fused_kernel<<<dim3(NCH, BATCH), 256, 0, stream>>>(
      enc_feat, enc_out, dec, v, mask, part, sums);
  reduce_kernel<<<BATCH, 256, 0, stream>>>(part, sums, out);
}

// Round 8
// 164.974 us; speedup vs baseline: 1.4835x; 1.4835x over previous
//
#include <hip/hip_runtime.h>

#define H2    1024
#define LSRC  1024
#define BATCH 64

__device__ __forceinline__ float fast_tanh(float x) {
  // tanh(x) = 1 - 2/(exp(2x)+1); saturates correctly (exp->inf => 1, exp->0 => -1)
  float e2 = __expf(2.0f * x);
  return 1.0f - 2.0f * __builtin_amdgcn_rcpf(e2 + 1.0f);
}

// dec[b][h] = sum_k s[b][k] * W[h][k] + bias[h]   (known-good round-4 version)
__global__ __launch_bounds__(256) void dec_kernel(
    const float* __restrict__ s, const float* __restrict__ W,
    const float* __restrict__ bias, float* __restrict__ dec) {
  const int KT = 128;
  __shared__ float s_lds[BATCH][KT + 1];
  __shared__ float w_lds[16][KT];
  const int t  = threadIdx.x;
  const int h0 = blockIdx.x * 16;
  const int bi = t & 63;
  const int hg = t >> 6;  // 0..3
  float acc[4] = {0.f, 0.f, 0.f, 0.f};
  for (int k0 = 0; k0 < H2; k0 += KT) {
    __syncthreads();
    for (int idx = t; idx < BATCH * KT; idx += 256) {
      int r = idx >> 7, c = idx & (KT - 1);
      s_lds[r][c] = s[r * H2 + k0 + c];
    }
    for (int idx = t; idx < 16 * KT; idx += 256) {
      int r = idx >> 7, c = idx & (KT - 1);
      w_lds[r][c] = W[(h0 + r) * H2 + k0 + c];
    }
    __syncthreads();
    for (int k = 0; k < KT; ++k) {
      float sv = s_lds[bi][k];
#pragma unroll
      for (int j = 0; j < 4; ++j) acc[j] += sv * w_lds[hg + 4 * j][k];
    }
  }
#pragma unroll
  for (int j = 0; j < 4; ++j) {
    int h = h0 + hg + 4 * j;
    dec[bi * H2 + h] = acc[j] + bias[h];
  }
}

// w[b][l] = exp(e[b][l])*mask[b][l]   (shift-free: |e| <= ||v||_1 ~ 16.4; clamp 80)
// GRID-STRIDE over rows: wave gw handles rows gw + 8192*k (k=0..7), so at any
// instant the whole GPU reads one contiguous ~32MB row window (probe-shaped),
// not 2048 scattered per-block chunks.
__global__ __launch_bounds__(256, 4) void e_kernel(
    const float* __restrict__ ef, const float* __restrict__ dec,
    const float* __restrict__ v, const float* __restrict__ mask,
    float* __restrict__ wbuf) {
  __shared__ float v_lds[H2];
  const int t    = threadIdx.x;
  const int lane = t & 63;
  const int wave = t >> 6;
  const int gw   = blockIdx.x * 4 + wave;  // 0..8191

  ((float4*)v_lds)[t] = ((const float4*)v)[t];
  __syncthreads();
  float4 vv0 = ((const float4*)v_lds)[lane];
  float4 vv1 = ((const float4*)v_lds)[lane + 64];
  float4 vv2 = ((const float4*)v_lds)[lane + 128];
  float4 vv3 = ((const float4*)v_lds)[lane + 192];

#pragma unroll
  for (int k = 0; k < 8; ++k) {
    const int r = gw + 8192 * k;       // row in [0, 65536)
    const int b = r >> 10;
    const float4* row  = (const float4*)(ef) + (size_t)r * 256 + lane;
    const float4* dec4 = (const float4*)(dec) + (size_t)b * 256 + lane;
    // 8 independent loads in flight: 4 ef (HBM stream) + 4 dec (L2)
    float4 x0 = row[0],    x1 = row[64],   x2 = row[128],  x3 = row[192];
    float4 d0 = dec4[0],   d1 = dec4[64],  d2 = dec4[128], d3 = dec4[192];
    float sum = 0.f;
    sum += fast_tanh(x0.x + d0.x) * vv0.x + fast_tanh(x0.y + d0.y) * vv0.y +
           fast_tanh(x0.z + d0.z) * vv0.z + fast_tanh(x0.w + d0.w) * vv0.w;
    sum += fast_tanh(x1.x + d1.x) * vv1.x + fast_tanh(x1.y + d1.y) * vv1.y +
           fast_tanh(x1.z + d1.z) * vv1.z + fast_tanh(x1.w + d1.w) * vv1.w;
    sum += fast_tanh(x2.x + d2.x) * vv2.x + fast_tanh(x2.y + d2.y) * vv2.y +
           fast_tanh(x2.z + d2.z) * vv2.z + fast_tanh(x2.w + d2.w) * vv2.w;
    sum += fast_tanh(x3.x + d3.x) * vv3.x + fast_tanh(x3.y + d3.y) * vv3.y +
           fast_tanh(x3.z + d3.z) * vv3.z + fast_tanh(x3.w + d3.w) * vv3.w;
#pragma unroll
    for (int off = 32; off; off >>= 1) sum += __shfl_xor(sum, off);
    float mk = mask[r];  // wave-uniform address -> scalar load
    if (lane == 0) wbuf[r] = __expf(fminf(sum, 80.f)) * mk;
  }
}

// part[b*32+lb][hq] = sum_{k} w[b][lb+32k] * eo[b][lb+32k][hq]
// At step k, ALL blocks read rows [32k, 32k+32) of their b: 64 compact
// advancing fronts (one per b) instead of 2048 scattered chunks.
__global__ __launch_bounds__(256, 4) void ct_kernel(
    const float* __restrict__ eo, const float* __restrict__ wbuf,
    float* __restrict__ part) {
  const int t  = threadIdx.x;
  const int b  = blockIdx.x >> 5;
  const int lb = blockIdx.x & 31;
  const float4* eob = (const float4*)(eo) + ((size_t)b * LSRC + lb) * 256 + t;
  const float*  wb  = wbuf + b * LSRC + lb;
  float4 acc = {0.f, 0.f, 0.f, 0.f};
#pragma unroll
  for (int k = 0; k < 32; k += 4) {
    // 4 independent 1KB/wave loads in flight; weights are uniform -> s_load
    float  w0 = wb[32 * k];
    float  w1 = wb[32 * (k + 1)];
    float  w2 = wb[32 * (k + 2)];
    float  w3 = wb[32 * (k + 3)];
    float4 x0 = eob[(size_t)(32 * k) * 256];
    float4 x1 = eob[(size_t)(32 * (k + 1)) * 256];
    float4 x2 = eob[(size_t)(32 * (k + 2)) * 256];
    float4 x3 = eob[(size_t)(32 * (k + 3)) * 256];
    acc.x += w0 * x0.x; acc.y += w0 * x0.y; acc.z += w0 * x0.z; acc.w += w0 * x0.w;
    acc.x += w1 * x1.x; acc.y += w1 * x1.y; acc.z += w1 * x1.z; acc.w += w1 * x1.w;
    acc.x += w2 * x2.x; acc.y += w2 * x2.y; acc.z += w2 * x2.z; acc.w += w2 * x2.w;
    acc.x += w3 * x3.x; acc.y += w3 * x3.y; acc.z += w3 * x3.z; acc.w += w3 * x3.w;
  }
  ((float4*)(part))[(size_t)blockIdx.x * 256 + t] = acc;
}

// out[b][hq] = (sum_lb part[b*32+lb][hq]) / (sum_l w[b][l])
__global__ __launch_bounds__(256) void reduce_kernel(
    const float* __restrict__ part, const float* __restrict__ wbuf,
    float* __restrict__ out) {
  __shared__ float wsum[4];
  const int b = blockIdx.x, t = threadIdx.x;
  const int lane = t & 63, wave = t >> 6;
  // Z = sum of this b's 1024 weights (4 KB)
  float4 wv = ((const float4*)(wbuf + b * LSRC))[t];
  float z = wv.x + wv.y + wv.z + wv.w;
#pragma unroll
  for (int off = 32; off; off >>= 1) z += __shfl_xor(z, off);
  if (lane == 0) wsum[wave] = z;
  __syncthreads();
  float inv = 1.0f / (wsum[0] + wsum[1] + wsum[2] + wsum[3]);
  float4 s = {0.f, 0.f, 0.f, 0.f};
#pragma unroll
  for (int lb = 0; lb < 32; ++lb) {
    float4 x = ((const float4*)(part))[(size_t)(b * 32 + lb) * 256 + t];
    s.x += x.x; s.y += x.y; s.z += x.z; s.w += x.w;
  }
  float4 o = {s.x * inv, s.y * inv, s.z * inv, s.w * inv};
  ((float4*)(out) + (size_t)b * 256)[t] = o;
}

extern "C" void kernel_launch(void* const* d_in, const int* in_sizes, int n_in,
                              void* d_out, int out_size, void* d_ws, size_t ws_size,
                              hipStream_t stream) {
  const float* s_t_hat  = (const float*)d_in[0];
  const float* enc_out  = (const float*)d_in[1];
  const float* enc_feat = (const float*)d_in[2];
  const float* mask     = (const float*)d_in[3];
  const float* W        = (const float*)d_in[4];
  const float* bias     = (const float*)d_in[5];
  const float* v        = (const float*)d_in[6];
  float* out = (float*)d_out;

  // ws layout (fp32): dec[64K] | wbuf[64K] | part[2048*256 float4 = 8MB]
  float* dec  = (float*)d_ws;
  float* wbuf = dec + BATCH * H2;
  float* part = wbuf + BATCH * LSRC;

  dec_kernel<<<H2 / 16, 256, 0, stream>>>(s_t_hat, W, bias, dec);
  e_kernel<<<2048, 256, 0, stream>>>(enc_feat, dec, v, mask, wbuf);
  ct_kernel<<<2048, 256, 0, stream>>>(enc_out, wbuf, part);
  reduce_kernel<<<BATCH, 256, 0, stream>>>(part, wbuf, out);
}